// Round 2
// baseline (284.054 us; speedup 1.0000x reference)
//
#include <hip/hip_runtime.h>
#include <hip/hip_bf16.h>
#include <math.h>

#define TB 2048   // sequence length
#define NB 4      // batch
#define NH 8      // heads
#define HD 96     // head dim
#define KD 768    // model dim

typedef unsigned short u16;
typedef __attribute__((ext_vector_type(8))) u16 u16x8;
typedef __attribute__((ext_vector_type(4))) float f32x4;
typedef __attribute__((ext_vector_type(8))) __bf16 bf16x8;

__device__ __forceinline__ u16 f2bf(float f) {
    unsigned u = __builtin_bit_cast(unsigned, f);
    u += 0x7FFFu + ((u >> 16) & 1u);   // RNE
    return (u16)(u >> 16);
}
__device__ __forceinline__ bf16x8 cast8(u16x8 u) { return __builtin_bit_cast(bf16x8, u); }

// ---------------------------------------------------------------------------
// Kernel A: QKV projection.  x[b][t][h][96] (fp32) x W^T (96x96) -> bf16.
// Output layout [b][h][t][96] so attention reads are contiguous per (b,h).
// inv4 baked into Wq, Wk.  grid = 65536/64 blocks, 256 thr (4 waves x 16 rows)
// ---------------------------------------------------------------------------
__global__ __launch_bounds__(256) void qkv_proj(
    const float* __restrict__ x, const float* __restrict__ Wq,
    const float* __restrict__ Wk, const float* __restrict__ Wv,
    u16* __restrict__ Q, u16* __restrict__ Kout, u16* __restrict__ V, float inv4)
{
    __shared__ __align__(16) u16 Wl[3][96][104];   // padded stride: 2-way banks
    const int tid = threadIdx.x;
    for (int idx = tid; idx < 3 * 9216; idx += 256) {
        int m = idx / 9216, rem = idx % 9216;
        const float* Wsrc = (m == 0) ? Wq : (m == 1) ? Wk : Wv;
        float scale = (m < 2) ? inv4 : 1.0f;
        int r = rem / 96, c = rem % 96;
        Wl[m][r][c] = f2bf(Wsrc[rem] * scale);
    }
    __syncthreads();

    const int w = tid >> 6, l = tid & 63;
    const int lc = l & 15, lk = l >> 4;
    const int r0 = blockIdx.x * 64 + w * 16;

    // A fragments: row = r0+lc, k = c*32 + 8*lk + j
    bf16x8 afrag[3];
    {
        const float* xp = x + (long)(r0 + lc) * 96 + 8 * lk;
#pragma unroll
        for (int c = 0; c < 3; ++c) {
            f32x4 f0 = *(const f32x4*)(xp + c * 32);
            f32x4 f1 = *(const f32x4*)(xp + c * 32 + 4);
            u16x8 u;
#pragma unroll
            for (int j = 0; j < 4; ++j) { u[j] = f2bf(f0[j]); u[4 + j] = f2bf(f1[j]); }
            afrag[c] = cast8(u);
        }
    }

    u16* outs[3] = {Q, Kout, V};
#pragma unroll
    for (int m = 0; m < 3; ++m) {
        f32x4 acc[6];
        const f32x4 Z4 = {0.f, 0.f, 0.f, 0.f};
#pragma unroll
        for (int nt = 0; nt < 6; ++nt) acc[nt] = Z4;
#pragma unroll
        for (int c = 0; c < 3; ++c) {
#pragma unroll
            for (int nt = 0; nt < 6; ++nt) {
                u16x8 bu = *(const u16x8*)&Wl[m][nt * 16 + lc][c * 32 + 8 * lk];
                acc[nt] = __builtin_amdgcn_mfma_f32_16x16x32_bf16(afrag[c], cast8(bu), acc[nt], 0, 0, 0);
            }
        }
        // D layout: row = r0 + lk*4 + reg, col = nt*16 + lc
#pragma unroll
        for (int reg = 0; reg < 4; ++reg) {
            int qr = r0 + lk * 4 + reg;              // (b*T + t)*H + h
            int b = qr >> 14, t = (qr >> 3) & (TB - 1), h = qr & 7;
            u16* op = outs[m] + ((long)((b * NH + h) * TB + t)) * 96;
#pragma unroll
            for (int nt = 0; nt < 6; ++nt)
                op[nt * 16 + lc] = f2bf(acc[nt][reg]);
        }
    }
}

// ---------------------------------------------------------------------------
// Kernel B: flash attention per (b,h).  Q-tile = 128 rows (8 waves x 16),
// K/V tiles of 64.  grid = (16 qtiles, 32 bh), 512 threads.
// ---------------------------------------------------------------------------
__global__ __launch_bounds__(512) void attn(
    const u16* __restrict__ Q, const u16* __restrict__ Kin, const u16* __restrict__ V,
    u16* __restrict__ O)
{
    __shared__ __align__(16) u16 Kl[64][104];     // K tile, row-major [s][d]
    __shared__ __align__(16) u16 Vt[96][72];      // V tile transposed [d][s]
    __shared__ __align__(16) u16 Pl[8][16][72];   // per-wave P transpose buf [q][s]

    const int tid = threadIdx.x;
    const int w = tid >> 6, l = tid & 63;
    const int lc = l & 15, lk = l >> 4;
    const int bh = blockIdx.y;
    const int q0 = blockIdx.x * 128 + w * 16;

    const u16* Qb = Q + (long)bh * TB * 96;
    const u16* Kb = Kin + (long)bh * TB * 96;
    const u16* Vb = V + (long)bh * TB * 96;

    // Q fragments held in registers for the whole kernel
    bf16x8 aq[3];
#pragma unroll
    for (int c = 0; c < 3; ++c)
        aq[c] = cast8(*(const u16x8*)(Qb + (long)(q0 + lc) * 96 + c * 32 + 8 * lk));

    float m_st[4], l_st[4];
    f32x4 accO[6];
    const f32x4 Z4 = {0.f, 0.f, 0.f, 0.f};
#pragma unroll
    for (int r = 0; r < 4; ++r) { m_st[r] = -1e30f; l_st[r] = 0.f; }
#pragma unroll
    for (int nt = 0; nt < 6; ++nt) accO[nt] = Z4;

    for (int st = 0; st < TB / 64; ++st) {
        const int s0 = st * 64;
        __syncthreads();   // previous tile's LDS reads done
        // stage K (coalesced, row-major) and V (transposed into Vt)
        for (int ch = tid; ch < 1536; ch += 512) {
            if (ch < 768) {
                int row = ch / 12, cc = (ch % 12) * 8;
                *(u16x8*)&Kl[row][cc] = *(const u16x8*)(Kb + (long)(s0 + row) * 96 + cc);
            } else {
                int c2 = ch - 768;
                int row = c2 & 63, cc = (c2 >> 6) * 8;  // row-linear: conflict-free LDS writes
                u16x8 v8 = *(const u16x8*)(Vb + (long)(s0 + row) * 96 + cc);
#pragma unroll
                for (int j = 0; j < 8; ++j) Vt[cc + j][row] = v8[j];
            }
        }
        __syncthreads();

        // S = Q K^T : A = Q rows (lc), B[k=d][col=s] = K[s][d] -> contiguous Kl row reads
        f32x4 s[4];
#pragma unroll
        for (int nt = 0; nt < 4; ++nt) s[nt] = Z4;
#pragma unroll
        for (int c = 0; c < 3; ++c) {
#pragma unroll
            for (int nt = 0; nt < 4; ++nt) {
                u16x8 bk = *(const u16x8*)&Kl[nt * 16 + lc][c * 32 + 8 * lk];
                s[nt] = __builtin_amdgcn_mfma_f32_16x16x32_bf16(aq[c], cast8(bk), s[nt], 0, 0, 0);
            }
        }

        // online softmax over rows (row = lk*4+reg held across 16 lanes)
        float alpha[4], p[4][4];
#pragma unroll
        for (int reg = 0; reg < 4; ++reg) {
            float mt = fmaxf(fmaxf(s[0][reg], s[1][reg]), fmaxf(s[2][reg], s[3][reg]));
#pragma unroll
            for (int msk = 1; msk < 16; msk <<= 1)
                mt = fmaxf(mt, __shfl_xor(mt, msk));
            float mnew = fmaxf(m_st[reg], mt);
            alpha[reg] = __expf(m_st[reg] - mnew);
            m_st[reg] = mnew;
            float sum = 0.f;
#pragma unroll
            for (int nt = 0; nt < 4; ++nt) {
                float pv = __expf(s[nt][reg] - mnew);
                p[nt][reg] = pv;
                sum += pv;
            }
#pragma unroll
            for (int msk = 1; msk < 16; msk <<= 1)
                sum += __shfl_xor(sum, msk);
            l_st[reg] = l_st[reg] * alpha[reg] + sum;
        }
        // transpose P into per-wave LDS region (bf16)
#pragma unroll
        for (int nt = 0; nt < 4; ++nt)
#pragma unroll
            for (int reg = 0; reg < 4; ++reg)
                Pl[w][lk * 4 + reg][nt * 16 + lc] = f2bf(p[nt][reg]);
        // rescale O while the P writes drain
#pragma unroll
        for (int nt = 0; nt < 6; ++nt)
#pragma unroll
            for (int reg = 0; reg < 4; ++reg)
                accO[nt][reg] *= alpha[reg];
        asm volatile("s_waitcnt lgkmcnt(0)" ::: "memory");  // P writes visible to own wave's reads

        // O += P V : A = P rows (lc), B[k=s][col=d] = Vt[d][s] contiguous reads
#pragma unroll
        for (int c2 = 0; c2 < 2; ++c2) {
            bf16x8 pa = cast8(*(const u16x8*)&Pl[w][lc][c2 * 32 + 8 * lk]);
#pragma unroll
            for (int nt = 0; nt < 6; ++nt) {
                u16x8 bv = *(const u16x8*)&Vt[nt * 16 + lc][c2 * 32 + 8 * lk];
                accO[nt] = __builtin_amdgcn_mfma_f32_16x16x32_bf16(pa, cast8(bv), accO[nt], 0, 0, 0);
            }
        }
    }

    // epilogue: O /= l, write [b][t][h*96+d] bf16
    const int b = bh >> 3, h = bh & 7;
#pragma unroll
    for (int reg = 0; reg < 4; ++reg) {
        float inv = 1.0f / l_st[reg];
        int t = q0 + lk * 4 + reg;
        u16* op = O + ((long)(b * TB + t)) * KD + h * 96;
#pragma unroll
        for (int nt = 0; nt < 6; ++nt)
            op[nt * 16 + lc] = f2bf(accO[nt][reg] * inv);
    }
}

// ---------------------------------------------------------------------------
// Kernel C: out = O @ Wu^T + bu.  M=8192, N=768, K=768.  Block tile 64x128,
// BK=32, 256 thr (4 waves x 16 rows).  Wu converted fp32->bf16 during staging.
// ---------------------------------------------------------------------------
__global__ __launch_bounds__(256) void out_gemm(
    const u16* __restrict__ O, const float* __restrict__ Wu,
    const float* __restrict__ bu, float* __restrict__ out)
{
    __shared__ __align__(16) u16 Al[64][40];
    __shared__ __align__(16) u16 Bl[128][40];
    const int tid = threadIdx.x;
    const int w = tid >> 6, l = tid & 63;
    const int lc = l & 15, lk = l >> 4;
    const int m0 = blockIdx.x * 64, n0 = blockIdx.y * 128;

    f32x4 acc[8];
    const f32x4 Z4 = {0.f, 0.f, 0.f, 0.f};
#pragma unroll
    for (int nt = 0; nt < 8; ++nt) acc[nt] = Z4;

    for (int c0 = 0; c0 < KD; c0 += 32) {
        __syncthreads();
        {   // stage A tile 64x32 (bf16, coalesced 16B/lane)
            int row = tid >> 2, cc = (tid & 3) * 8;
            *(u16x8*)&Al[row][cc] = *(const u16x8*)(O + (long)(m0 + row) * KD + c0 + cc);
        }
        {   // stage B tile: Wu rows [n0,n0+128) x cols [c0,c0+32), fp32 -> bf16
            int row = tid >> 1, cc = (tid & 1) * 16;
            const float* src = Wu + (long)(n0 + row) * KD + c0 + cc;
            f32x4 f0 = *(const f32x4*)(src);
            f32x4 f1 = *(const f32x4*)(src + 4);
            f32x4 f2 = *(const f32x4*)(src + 8);
            f32x4 f3 = *(const f32x4*)(src + 12);
            u16x8 u0, u1;
#pragma unroll
            for (int j = 0; j < 4; ++j) {
                u0[j] = f2bf(f0[j]); u0[4 + j] = f2bf(f1[j]);
                u1[j] = f2bf(f2[j]); u1[4 + j] = f2bf(f3[j]);
            }
            *(u16x8*)&Bl[row][cc] = u0;
            *(u16x8*)&Bl[row][cc + 8] = u1;
        }
        __syncthreads();

        bf16x8 a = cast8(*(const u16x8*)&Al[w * 16 + lc][8 * lk]);
#pragma unroll
        for (int nt = 0; nt < 8; ++nt) {
            u16x8 bb = *(const u16x8*)&Bl[nt * 16 + lc][8 * lk];
            acc[nt] = __builtin_amdgcn_mfma_f32_16x16x32_bf16(a, cast8(bb), acc[nt], 0, 0, 0);
        }
    }

#pragma unroll
    for (int reg = 0; reg < 4; ++reg) {
        int r = m0 + w * 16 + lk * 4 + reg;
        float* op = out + (long)r * KD + n0;
#pragma unroll
        for (int nt = 0; nt < 8; ++nt)
            op[nt * 16 + lc] = acc[nt][reg] + bu[n0 + nt * 16 + lc];
    }
}

extern "C" void kernel_launch(void* const* d_in, const int* in_sizes, int n_in,
                              void* d_out, int out_size, void* d_ws, size_t ws_size,
                              hipStream_t stream) {
    const float* x  = (const float*)d_in[0];
    const float* Wq = (const float*)d_in[1];
    const float* Wk = (const float*)d_in[2];
    const float* Wv = (const float*)d_in[3];
    const float* Wu = (const float*)d_in[4];
    const float* bu = (const float*)d_in[5];
    float* out = (float*)d_out;

    u16* ws = (u16*)d_ws;
    const size_t SZ = (size_t)NB * NH * TB * 96;   // per-tensor bf16 elems
    u16* Q  = ws;
    u16* Kq = ws + SZ;
    u16* V  = ws + 2 * SZ;
    u16* O  = ws + 3 * SZ;

    const float inv4 = 1.0f / powf((float)KD, 0.25f);

    qkv_proj<<<dim3((NB * TB * NH) / 64), dim3(256), 0, stream>>>(x, Wq, Wk, Wv, Q, Kq, V, inv4);
    attn<<<dim3(TB / 128, NB * NH), dim3(512), 0, stream>>>(Q, Kq, V, O);
    out_gemm<<<dim3((NB * TB) / 64, KD / 128), dim3(256), 0, stream>>>(O, Wu, bu, out);
}

// Round 4
// 227.429 us; speedup vs baseline: 1.2490x; 1.2490x over previous
//
#include <hip/hip_runtime.h>
#include <hip/hip_bf16.h>
#include <math.h>

#define TB 2048   // sequence length
#define NB 4      // batch
#define NH 8      // heads
#define HD 96     // head dim
#define KD 768    // model dim

typedef unsigned short u16;
typedef __attribute__((ext_vector_type(4))) u16 u16x4;
typedef __attribute__((ext_vector_type(8))) u16 u16x8;
typedef __attribute__((ext_vector_type(4))) float f32x4;
typedef __attribute__((ext_vector_type(8))) __bf16 bf16x8;

__device__ __forceinline__ u16 f2bf(float f) {
    unsigned u = __builtin_bit_cast(unsigned, f);
    u += 0x7FFFu + ((u >> 16) & 1u);   // RNE
    return (u16)(u >> 16);
}
__device__ __forceinline__ bf16x8 cast8(u16x8 u) { return __builtin_bit_cast(bf16x8, u); }

// ---------------------------------------------------------------------------
// Kernel A: QKV projection.  Block = one (b,h,t-chunk of 64).
//   Q,K -> [bh][t][96]   (D = x*W^T, rows = t)
//   V   -> [bh][96][t]   (transposed: D = W*x^T via swapped MFMA args, rows = d)
// inv4 baked into Wq,Wk.  grid = (32 t-chunks, 32 bh), 256 thr.
// ---------------------------------------------------------------------------
__global__ __launch_bounds__(256) void qkv_proj(
    const float* __restrict__ x, const float* __restrict__ Wq,
    const float* __restrict__ Wk, const float* __restrict__ Wv,
    u16* __restrict__ Q, u16* __restrict__ Kout, u16* __restrict__ VT, float inv4)
{
    __shared__ __align__(16) u16 Wl[3][96][104];   // padded stride: ~2-way banks
    const int tid = threadIdx.x;
    for (int idx = tid; idx < 3 * 9216; idx += 256) {
        int m = idx / 9216, rem = idx % 9216;
        const float* Wsrc = (m == 0) ? Wq : (m == 1) ? Wk : Wv;
        float scale = (m < 2) ? inv4 : 1.0f;
        int r = rem / 96, c = rem % 96;
        Wl[m][r][c] = f2bf(Wsrc[rem] * scale);
    }
    __syncthreads();

    const int w = tid >> 6, l = tid & 63;
    const int lc = l & 15, lk = l >> 4;
    const int bh = blockIdx.y, b = bh >> 3, h = bh & 7;
    const int t0 = blockIdx.x * 64 + w * 16;

    // A fragments: row = t0+lc (x row for this (b,h)), k = c*32 + 8*lk + j
    bf16x8 afrag[3];
    {
        const float* xp = x + ((long)((b * TB + t0 + lc) * NH + h)) * HD + 8 * lk;
#pragma unroll
        for (int c = 0; c < 3; ++c) {
            f32x4 f0 = *(const f32x4*)(xp + c * 32);
            f32x4 f1 = *(const f32x4*)(xp + c * 32 + 4);
            u16x8 u;
#pragma unroll
            for (int j = 0; j < 4; ++j) { u[j] = f2bf(f0[j]); u[4 + j] = f2bf(f1[j]); }
            afrag[c] = cast8(u);
        }
    }

    const f32x4 Z4 = {0.f, 0.f, 0.f, 0.f};
    // ---- Q and K: D[t][o] ----
    u16* outs[2] = {Q, Kout};
#pragma unroll
    for (int m = 0; m < 2; ++m) {
        f32x4 acc[6];
#pragma unroll
        for (int nt = 0; nt < 6; ++nt) acc[nt] = Z4;
#pragma unroll
        for (int c = 0; c < 3; ++c) {
#pragma unroll
            for (int nt = 0; nt < 6; ++nt) {
                u16x8 bw = *(const u16x8*)&Wl[m][nt * 16 + lc][c * 32 + 8 * lk];
                acc[nt] = __builtin_amdgcn_mfma_f32_16x16x32_bf16(afrag[c], cast8(bw), acc[nt], 0, 0, 0);
            }
        }
#pragma unroll
        for (int reg = 0; reg < 4; ++reg) {
            int t = t0 + lk * 4 + reg;
            u16* op = outs[m] + ((long)bh * TB + t) * HD;
#pragma unroll
            for (int nt = 0; nt < 6; ++nt)
                op[nt * 16 + lc] = f2bf(acc[nt][reg]);
        }
    }
    // ---- V: swapped args -> D[o][t], store transposed [bh][d][t] ----
    {
        f32x4 acc[6];
#pragma unroll
        for (int nt = 0; nt < 6; ++nt) acc[nt] = Z4;
#pragma unroll
        for (int c = 0; c < 3; ++c) {
#pragma unroll
            for (int nt = 0; nt < 6; ++nt) {
                u16x8 aw = *(const u16x8*)&Wl[2][nt * 16 + lc][c * 32 + 8 * lk];
                acc[nt] = __builtin_amdgcn_mfma_f32_16x16x32_bf16(cast8(aw), afrag[c], acc[nt], 0, 0, 0);
            }
        }
#pragma unroll
        for (int nt = 0; nt < 6; ++nt)
#pragma unroll
            for (int reg = 0; reg < 4; ++reg) {
                int o = nt * 16 + lk * 4 + reg;
                VT[((long)bh * HD + o) * TB + t0 + lc] = f2bf(acc[nt][reg]);
            }
    }
}

// ---------------------------------------------------------------------------
// Kernel B: flash attention per (b,h).  Q-tile = 128 (8 waves x 16 q-rows),
// K/V tiles of 64.  Swapped QK^T -> in-register softmax.  T14 async staging.
// grid = (16 qtiles, 32 bh), 512 threads.
// ---------------------------------------------------------------------------
__global__ __launch_bounds__(512) void attn(
    const u16* __restrict__ Q, const u16* __restrict__ Kin, const u16* __restrict__ VT,
    u16* __restrict__ O)
{
    __shared__ __align__(16) u16 Kl[64][104];     // K tile [s][d]
    __shared__ __align__(16) u16 Vt[96][72];      // V tile transposed [d][s]
    __shared__ __align__(16) u16 Pl[8][16][72];   // per-wave P buf [q][s]

    const int tid = threadIdx.x;
    const int w = tid >> 6, l = tid & 63;
    const int lc = l & 15, lk = l >> 4;
    const int bh = blockIdx.y;
    const int q0 = blockIdx.x * 128 + w * 16;

    const u16* Qb = Q + (long)bh * TB * HD;
    const u16* Kb = Kin + (long)bh * TB * HD;
    const u16* Vb = VT + (long)bh * HD * TB;    // [d][t]

    // staging descriptors: 3 b128 chunks per thread (K: 768 chunks, Vt: 768)
    const u16* gbase[3]; u16* lptr[3]; int mult[3];
#pragma unroll
    for (int ci = 0; ci < 3; ++ci) {
        int ch = tid + ci * 512;
        if (ch < 768) {
            int row = ch / 12, cc = (ch % 12) * 8;
            gbase[ci] = Kb + row * HD + cc;    // + s0*96
            mult[ci] = HD;
            lptr[ci] = &Kl[row][cc];
        } else {
            int c2 = ch - 768;
            int d = c2 >> 3, sc = (c2 & 7) * 8;
            gbase[ci] = Vb + (long)d * TB + sc;  // + s0
            mult[ci] = 1;
            lptr[ci] = &Vt[d][sc];
        }
    }

    // Q fragments in registers (also the B-operand of swapped QK^T)
    bf16x8 aq[3];
#pragma unroll
    for (int c = 0; c < 3; ++c)
        aq[c] = cast8(*(const u16x8*)(Qb + (long)(q0 + lc) * HD + c * 32 + 8 * lk));

    // prologue: load tile 0 into regs
    u16x8 r[3];
#pragma unroll
    for (int ci = 0; ci < 3; ++ci) r[ci] = *(const u16x8*)(gbase[ci]);

    float m_st = -1e30f, l_st = 0.f;   // per-lane: q-row = lc
    f32x4 accO[6];
    const f32x4 Z4 = {0.f, 0.f, 0.f, 0.f};
#pragma unroll
    for (int nt = 0; nt < 6; ++nt) accO[nt] = Z4;

    for (int st = 0; st < TB / 64; ++st) {
        __syncthreads();   // previous tile's LDS reads done
#pragma unroll
        for (int ci = 0; ci < 3; ++ci) *(u16x8*)lptr[ci] = r[ci];
        // issue next tile's loads (latency hides under compute below)
        int s1 = (st + 1) * 64; if (s1 > TB - 64) s1 = TB - 64;
#pragma unroll
        for (int ci = 0; ci < 3; ++ci) r[ci] = *(const u16x8*)(gbase[ci] + (long)s1 * mult[ci]);
        __syncthreads();

        // S^T = K Q^T : A = K rows (s = nt*16+lc), B = Q (col q = lc)
        f32x4 s[4];
#pragma unroll
        for (int nt = 0; nt < 4; ++nt) s[nt] = Z4;
#pragma unroll
        for (int c = 0; c < 3; ++c) {
#pragma unroll
            for (int nt = 0; nt < 4; ++nt) {
                u16x8 kf = *(const u16x8*)&Kl[nt * 16 + lc][c * 32 + 8 * lk];
                s[nt] = __builtin_amdgcn_mfma_f32_16x16x32_bf16(cast8(kf), aq[c], s[nt], 0, 0, 0);
            }
        }
        // lane holds S[s = nt*16 + lk*4 + reg][q = lc]: 16 of 64 s-values.
        // reduce across the 4 lk-groups with 2 shuffles.
        float tm = -1e30f;
#pragma unroll
        for (int nt = 0; nt < 4; ++nt)
#pragma unroll
            for (int reg = 0; reg < 4; ++reg) tm = fmaxf(tm, s[nt][reg]);
        tm = fmaxf(tm, __shfl_xor(tm, 16));
        tm = fmaxf(tm, __shfl_xor(tm, 32));
        float mnew = fmaxf(m_st, tm);
        float alpha = __expf(m_st - mnew);
        m_st = mnew;
        float p[4][4]; float sum = 0.f;
#pragma unroll
        for (int nt = 0; nt < 4; ++nt)
#pragma unroll
            for (int reg = 0; reg < 4; ++reg) {
                float pv = __expf(s[nt][reg] - mnew);
                p[nt][reg] = pv;
                sum += pv;
            }
        sum += __shfl_xor(sum, 16);
        sum += __shfl_xor(sum, 32);
        l_st = l_st * alpha + sum;

        // P^T -> Pl[q][s], packed b64 (s = nt*16 + lk*4 + reg contiguous in reg)
#pragma unroll
        for (int nt = 0; nt < 4; ++nt) {
            u16x4 pk = { f2bf(p[nt][0]), f2bf(p[nt][1]), f2bf(p[nt][2]), f2bf(p[nt][3]) };
            *(u16x4*)&Pl[w][lc][nt * 16 + lk * 4] = pk;
        }
        // rescale accO rows (q = lk*4+reg) by that row's alpha
        float ar[4];
#pragma unroll
        for (int reg = 0; reg < 4; ++reg) ar[reg] = __shfl(alpha, lk * 4 + reg, 16);
#pragma unroll
        for (int nt = 0; nt < 6; ++nt)
#pragma unroll
            for (int reg = 0; reg < 4; ++reg) accO[nt][reg] *= ar[reg];
        asm volatile("s_waitcnt lgkmcnt(0)" ::: "memory");  // Pl writes visible

        // O += P V : A = P rows (q=lc), B = Vt (col d = lc)
#pragma unroll
        for (int c2 = 0; c2 < 2; ++c2) {
            bf16x8 pa = cast8(*(const u16x8*)&Pl[w][lc][c2 * 32 + 8 * lk]);
#pragma unroll
            for (int nt = 0; nt < 6; ++nt) {
                u16x8 bv = *(const u16x8*)&Vt[nt * 16 + lc][c2 * 32 + 8 * lk];
                accO[nt] = __builtin_amdgcn_mfma_f32_16x16x32_bf16(pa, cast8(bv), accO[nt], 0, 0, 0);
            }
        }
    }

    // epilogue: accO rows q = lk*4+reg need l_st held at lane lc' = q
    const int b = bh >> 3, h = bh & 7;
    float linv[4];
#pragma unroll
    for (int reg = 0; reg < 4; ++reg) linv[reg] = 1.0f / __shfl(l_st, lk * 4 + reg, 16);
#pragma unroll
    for (int reg = 0; reg < 4; ++reg) {
        int t = q0 + lk * 4 + reg;
        u16* op = O + ((long)(b * TB + t)) * KD + h * HD;
#pragma unroll
        for (int nt = 0; nt < 6; ++nt)
            op[nt * 16 + lc] = f2bf(accO[nt][reg] * linv[reg]);
    }
}

// ---------------------------------------------------------------------------
// Kernel C: out = O @ Wu^T + bu.  M=8192, N=768, K=768.  Block tile 64x128,
// BK=32, 256 thr (4 waves x 16 rows).  Wu converted fp32->bf16 during staging.
// ---------------------------------------------------------------------------
__global__ __launch_bounds__(256) void out_gemm(
    const u16* __restrict__ O, const float* __restrict__ Wu,
    const float* __restrict__ bu, float* __restrict__ out)
{
    __shared__ __align__(16) u16 Al[64][40];
    __shared__ __align__(16) u16 Bl[128][40];
    const int tid = threadIdx.x;
    const int w = tid >> 6, l = tid & 63;
    const int lc = l & 15, lk = l >> 4;
    const int m0 = blockIdx.x * 64, n0 = blockIdx.y * 128;

    f32x4 acc[8];
    const f32x4 Z4 = {0.f, 0.f, 0.f, 0.f};
#pragma unroll
    for (int nt = 0; nt < 8; ++nt) acc[nt] = Z4;

    for (int c0 = 0; c0 < KD; c0 += 32) {
        __syncthreads();
        {   // stage A tile 64x32 (bf16, coalesced 16B/lane)
            int row = tid >> 2, cc = (tid & 3) * 8;
            *(u16x8*)&Al[row][cc] = *(const u16x8*)(O + (long)(m0 + row) * KD + c0 + cc);
        }
        {   // stage B tile: Wu rows [n0,n0+128) x cols [c0,c0+32), fp32 -> bf16
            int row = tid >> 1, cc = (tid & 1) * 16;
            const float* src = Wu + (long)(n0 + row) * KD + c0 + cc;
            f32x4 f0 = *(const f32x4*)(src);
            f32x4 f1 = *(const f32x4*)(src + 4);
            f32x4 f2 = *(const f32x4*)(src + 8);
            f32x4 f3 = *(const f32x4*)(src + 12);
            u16x8 u0, u1;
#pragma unroll
            for (int j = 0; j < 4; ++j) {
                u0[j] = f2bf(f0[j]); u0[4 + j] = f2bf(f1[j]);
                u1[j] = f2bf(f2[j]); u1[4 + j] = f2bf(f3[j]);
            }
            *(u16x8*)&Bl[row][cc] = u0;
            *(u16x8*)&Bl[row][cc + 8] = u1;
        }
        __syncthreads();

        bf16x8 a = cast8(*(const u16x8*)&Al[w * 16 + lc][8 * lk]);
#pragma unroll
        for (int nt = 0; nt < 8; ++nt) {
            u16x8 bb = *(const u16x8*)&Bl[nt * 16 + lc][8 * lk];
            acc[nt] = __builtin_amdgcn_mfma_f32_16x16x32_bf16(a, cast8(bb), acc[nt], 0, 0, 0);
        }
    }

#pragma unroll
    for (int reg = 0; reg < 4; ++reg) {
        int rr = m0 + w * 16 + lk * 4 + reg;
        float* op = out + (long)rr * KD + n0;
#pragma unroll
        for (int nt = 0; nt < 8; ++nt)
            op[nt * 16 + lc] = acc[nt][reg] + bu[n0 + nt * 16 + lc];
    }
}

extern "C" void kernel_launch(void* const* d_in, const int* in_sizes, int n_in,
                              void* d_out, int out_size, void* d_ws, size_t ws_size,
                              hipStream_t stream) {
    const float* x  = (const float*)d_in[0];
    const float* Wq = (const float*)d_in[1];
    const float* Wk = (const float*)d_in[2];
    const float* Wv = (const float*)d_in[3];
    const float* Wu = (const float*)d_in[4];
    const float* bu = (const float*)d_in[5];
    float* out = (float*)d_out;

    u16* ws = (u16*)d_ws;
    const size_t SZ = (size_t)NB * NH * TB * HD;   // per-tensor bf16 elems
    u16* Q  = ws;
    u16* Kq = ws + SZ;
    u16* VT = ws + 2 * SZ;   // [bh][96][2048]
    u16* O  = ws + 3 * SZ;

    const float inv4 = 1.0f / powf((float)KD, 0.25f);

    qkv_proj<<<dim3(TB / 64, NB * NH), dim3(256), 0, stream>>>(x, Wq, Wk, Wv, Q, Kq, VT, inv4);
    attn<<<dim3(TB / 128, NB * NH), dim3(512), 0, stream>>>(Q, Kq, VT, O);
    out_gemm<<<dim3((NB * TB) / 64, KD / 128), dim3(256), 0, stream>>>(O, Wu, bu, out);
}

// Round 6
// 199.337 us; speedup vs baseline: 1.4250x; 1.1409x over previous
//
#include <hip/hip_runtime.h>
#include <hip/hip_bf16.h>
#include <math.h>

#define TB 2048   // sequence length
#define NB 4      // batch
#define NH 8      // heads
#define HD 96     // head dim
#define KD 768    // model dim

typedef unsigned short u16;
typedef __attribute__((ext_vector_type(4))) u16 u16x4;
typedef __attribute__((ext_vector_type(8))) u16 u16x8;
typedef __attribute__((ext_vector_type(4))) float f32x4;
typedef __attribute__((ext_vector_type(16))) float f32x16;
typedef __attribute__((ext_vector_type(4))) unsigned u32x4;
typedef __attribute__((ext_vector_type(8))) __bf16 bf16x8;

__device__ __forceinline__ u16 f2bf(float f) {
    unsigned u = __builtin_bit_cast(unsigned, f);
    u += 0x7FFFu + ((u >> 16) & 1u);   // RNE
    return (u16)(u >> 16);
}
__device__ __forceinline__ bf16x8 cast8(u16x8 u) { return __builtin_bit_cast(bf16x8, u); }
__device__ __forceinline__ unsigned pkbf(float a, float b) {
    unsigned w;
    asm("v_cvt_pk_bf16_f32 %0, %1, %2" : "=v"(w) : "v"(a), "v"(b));
    return w;
}

// ---------------------------------------------------------------------------
// Kernel A: QKV projection.  Block = one (b,h,t-chunk of 64).
//   Q,K -> [bh][t][96]   (D = x*W^T, rows = t)
//   V   -> [bh][96][t]   (transposed: D = W*x^T via swapped MFMA args)
// inv4 baked into Wq,Wk.  grid = (32 t-chunks, 32 bh), 256 thr.
// ---------------------------------------------------------------------------
__global__ __launch_bounds__(256) void qkv_proj(
    const float* __restrict__ x, const float* __restrict__ Wq,
    const float* __restrict__ Wk, const float* __restrict__ Wv,
    u16* __restrict__ Q, u16* __restrict__ Kout, u16* __restrict__ VT, float inv4)
{
    __shared__ __align__(16) u16 Wl[3][96][104];
    const int tid = threadIdx.x;
    for (int idx = tid; idx < 3 * 9216; idx += 256) {
        int m = idx / 9216, rem = idx % 9216;
        const float* Wsrc = (m == 0) ? Wq : (m == 1) ? Wk : Wv;
        float scale = (m < 2) ? inv4 : 1.0f;
        int r = rem / 96, c = rem % 96;
        Wl[m][r][c] = f2bf(Wsrc[rem] * scale);
    }
    __syncthreads();

    const int w = tid >> 6, l = tid & 63;
    const int lc = l & 15, lk = l >> 4;
    const int bh = blockIdx.y, b = bh >> 3, h = bh & 7;
    const int t0 = blockIdx.x * 64 + w * 16;

    bf16x8 afrag[3];
    {
        const float* xp = x + ((long)((b * TB + t0 + lc) * NH + h)) * HD + 8 * lk;
#pragma unroll
        for (int c = 0; c < 3; ++c) {
            f32x4 f0 = *(const f32x4*)(xp + c * 32);
            f32x4 f1 = *(const f32x4*)(xp + c * 32 + 4);
            u16x8 u;
#pragma unroll
            for (int j = 0; j < 4; ++j) { u[j] = f2bf(f0[j]); u[4 + j] = f2bf(f1[j]); }
            afrag[c] = cast8(u);
        }
    }

    const f32x4 Z4 = {0.f, 0.f, 0.f, 0.f};
    u16* outs[2] = {Q, Kout};
#pragma unroll
    for (int m = 0; m < 2; ++m) {
        f32x4 acc[6];
#pragma unroll
        for (int nt = 0; nt < 6; ++nt) acc[nt] = Z4;
#pragma unroll
        for (int c = 0; c < 3; ++c) {
#pragma unroll
            for (int nt = 0; nt < 6; ++nt) {
                u16x8 bw = *(const u16x8*)&Wl[m][nt * 16 + lc][c * 32 + 8 * lk];
                acc[nt] = __builtin_amdgcn_mfma_f32_16x16x32_bf16(afrag[c], cast8(bw), acc[nt], 0, 0, 0);
            }
        }
#pragma unroll
        for (int reg = 0; reg < 4; ++reg) {
            int t = t0 + lk * 4 + reg;
            u16* op = outs[m] + ((long)bh * TB + t) * HD;
#pragma unroll
            for (int nt = 0; nt < 6; ++nt)
                op[nt * 16 + lc] = f2bf(acc[nt][reg]);
        }
    }
    {   // V transposed
        f32x4 acc[6];
#pragma unroll
        for (int nt = 0; nt < 6; ++nt) acc[nt] = Z4;
#pragma unroll
        for (int c = 0; c < 3; ++c) {
#pragma unroll
            for (int nt = 0; nt < 6; ++nt) {
                u16x8 aw = *(const u16x8*)&Wl[2][nt * 16 + lc][c * 32 + 8 * lk];
                acc[nt] = __builtin_amdgcn_mfma_f32_16x16x32_bf16(cast8(aw), afrag[c], acc[nt], 0, 0, 0);
            }
        }
#pragma unroll
        for (int nt = 0; nt < 6; ++nt)
#pragma unroll
            for (int reg = 0; reg < 4; ++reg) {
                int o = nt * 16 + lk * 4 + reg;
                VT[((long)bh * HD + o) * TB + t0 + lc] = f2bf(acc[nt][reg]);
            }
    }
}

// ---------------------------------------------------------------------------
// Kernel B: flash attention, 32x32 MFMA path.  Q-tile 256 (8 waves x 32 q),
// K/V tiles of 64.  Swapped QK^T; P rebuilt in-register (cvt_pk + shfl/select);
// defer-max (T13); T14 reg-staged K/V prefetch.  grid = (8, 32), 512 thr.
// ---------------------------------------------------------------------------
__global__ __launch_bounds__(512) void attn(
    const u16* __restrict__ Q, const u16* __restrict__ Kin, const u16* __restrict__ VT,
    u16* __restrict__ O)
{
    __shared__ __align__(16) u16 Kl[64][104];     // K tile [s][d]
    __shared__ __align__(16) u16 Vt[96][72];      // V tile transposed [d][s]

    const int tid = threadIdx.x;
    const int w = tid >> 6, l = tid & 63;
    const int m32 = l & 31, hi = l >> 5;
    const int bh = blockIdx.y;
    const int q0 = blockIdx.x * 256 + w * 32;

    const u16* Qb = Q + (long)bh * TB * HD;
    const u16* Kb = Kin + (long)bh * TB * HD;
    const u16* Vb = VT + (long)bh * HD * TB;    // [d][t]

    // staging descriptors: 3 b128 chunks/thread (K: 768 chunks, Vt: 768)
    const u16* gbase[3]; u16* lptr[3]; int mult[3];
#pragma unroll
    for (int ci = 0; ci < 3; ++ci) {
        int ch = tid + ci * 512;
        if (ch < 768) {
            int row = ch / 12, cc = (ch % 12) * 8;
            gbase[ci] = Kb + row * HD + cc;
            mult[ci] = HD;
            lptr[ci] = &Kl[row][cc];
        } else {
            int c2 = ch - 768;
            int d = c2 >> 3, sc = (c2 & 7) * 8;
            gbase[ci] = Vb + (long)d * TB + sc;
            mult[ci] = 1;
            lptr[ci] = &Vt[d][sc];
        }
    }

    // Q B-fragments: col q = q0+m32, k = kk*16 + 8*hi + j
    bf16x8 qb[6];
#pragma unroll
    for (int kk = 0; kk < 6; ++kk)
        qb[kk] = cast8(*(const u16x8*)(Qb + (long)(q0 + m32) * HD + kk * 16 + 8 * hi));

    u16x8 r[3];
#pragma unroll
    for (int ci = 0; ci < 3; ++ci) r[ci] = *(const u16x8*)(gbase[ci]);

    float m_st = -1e30f, l_st = 0.f;    // per-lane: q = q0 + m32
    f32x16 accO[3];                      // O^T[d-tile][q]
#pragma unroll
    for (int dt = 0; dt < 3; ++dt)
#pragma unroll
        for (int rr = 0; rr < 16; ++rr) accO[dt][rr] = 0.f;

    for (int st = 0; st < TB / 64; ++st) {
        __syncthreads();
#pragma unroll
        for (int ci = 0; ci < 3; ++ci) *(u16x8*)lptr[ci] = r[ci];
        int s1 = (st + 1) * 64; if (s1 > TB - 64) s1 = TB - 64;
#pragma unroll
        for (int ci = 0; ci < 3; ++ci) r[ci] = *(const u16x8*)(gbase[ci] + (long)s1 * mult[ci]);
        __syncthreads();

        // S^T = K Q^T, 32x32x16: A = K rows (s), B = Q cols (q)
        f32x16 sa[2];
#pragma unroll
        for (int st2 = 0; st2 < 2; ++st2) {
#pragma unroll
            for (int rr = 0; rr < 16; ++rr) sa[st2][rr] = 0.f;
#pragma unroll
            for (int kk = 0; kk < 6; ++kk) {
                u16x8 kf = *(const u16x8*)&Kl[st2 * 32 + m32][kk * 16 + 8 * hi];
                sa[st2] = __builtin_amdgcn_mfma_f32_32x32x16_bf16(cast8(kf), qb[kk], sa[st2], 0, 0, 0);
            }
        }

        // softmax: lane holds 32 s-values of q's column; other 32 at lane^32
        float tm = sa[0][0];
#pragma unroll
        for (int st2 = 0; st2 < 2; ++st2)
#pragma unroll
            for (int rr = 0; rr < 16; ++rr) tm = fmaxf(tm, sa[st2][rr]);
        tm = fmaxf(tm, __shfl_xor(tm, 32));
        if (!__all(tm - m_st <= 8.0f)) {   // T13 defer-max
            float mnew = fmaxf(m_st, tm);
            float alpha = __expf(m_st - mnew);
#pragma unroll
            for (int dt = 0; dt < 3; ++dt)
#pragma unroll
                for (int rr = 0; rr < 16; ++rr) accO[dt][rr] *= alpha;
            l_st *= alpha;
            m_st = mnew;
        }
        float sum = 0.f;
#pragma unroll
        for (int st2 = 0; st2 < 2; ++st2)
#pragma unroll
            for (int rr = 0; rr < 16; ++rr) {
                float pv = __expf(sa[st2][rr] - m_st);
                sa[st2][rr] = pv;
                sum += pv;
            }
        sum += __shfl_xor(sum, 32);
        l_st += sum;

        // P -> bf16 B-fragments in-register; PV accumulate
#pragma unroll
        for (int st2 = 0; st2 < 2; ++st2) {
            unsigned A1 = pkbf(sa[st2][0], sa[st2][1]);
            unsigned A2 = pkbf(sa[st2][2], sa[st2][3]);
            unsigned B1 = pkbf(sa[st2][4], sa[st2][5]);
            unsigned B2 = pkbf(sa[st2][6], sa[st2][7]);
            unsigned A3 = pkbf(sa[st2][8], sa[st2][9]);
            unsigned A4 = pkbf(sa[st2][10], sa[st2][11]);
            unsigned B3 = pkbf(sa[st2][12], sa[st2][13]);
            unsigned B4 = pkbf(sa[st2][14], sa[st2][15]);
            unsigned xA1 = __shfl_xor((int)A1, 32), xA2 = __shfl_xor((int)A2, 32);
            unsigned xB1 = __shfl_xor((int)B1, 32), xB2 = __shfl_xor((int)B2, 32);
            unsigned xA3 = __shfl_xor((int)A3, 32), xA4 = __shfl_xor((int)A4, 32);
            unsigned xB3 = __shfl_xor((int)B3, 32), xB4 = __shfl_xor((int)B4, 32);
            u32x4 t0 = { hi ? xB1 : A1, hi ? xB2 : A2, hi ? B1 : xA1, hi ? B2 : xA2 };
            u32x4 t1 = { hi ? xB3 : A3, hi ? xB4 : A4, hi ? B3 : xA3, hi ? B4 : xA4 };
            bf16x8 pb0 = __builtin_bit_cast(bf16x8, t0);   // k = st2*32 + 0..15
            bf16x8 pb1 = __builtin_bit_cast(bf16x8, t1);   // k = st2*32 + 16..31
#pragma unroll
            for (int dt = 0; dt < 3; ++dt) {
                u16x8 vfa = *(const u16x8*)&Vt[dt * 32 + m32][st2 * 32 + 8 * hi];
                accO[dt] = __builtin_amdgcn_mfma_f32_32x32x16_bf16(cast8(vfa), pb0, accO[dt], 0, 0, 0);
            }
#pragma unroll
            for (int dt = 0; dt < 3; ++dt) {
                u16x8 vfb = *(const u16x8*)&Vt[dt * 32 + m32][st2 * 32 + 16 + 8 * hi];
                accO[dt] = __builtin_amdgcn_mfma_f32_32x32x16_bf16(cast8(vfb), pb1, accO[dt], 0, 0, 0);
            }
        }
    }

    // epilogue: O^T[d][q] -> O[b][t=q][h*96+d], /= l_st
    const int b = bh >> 3, h = bh & 7;
    float linv = 1.0f / l_st;
    int t = q0 + m32;
    u16* op = O + ((long)(b * TB + t)) * KD + h * HD;
#pragma unroll
    for (int dt = 0; dt < 3; ++dt)
#pragma unroll
        for (int q4 = 0; q4 < 4; ++q4) {
            u16x4 v = { f2bf(accO[dt][q4 * 4 + 0] * linv), f2bf(accO[dt][q4 * 4 + 1] * linv),
                        f2bf(accO[dt][q4 * 4 + 2] * linv), f2bf(accO[dt][q4 * 4 + 3] * linv) };
            *(u16x4*)(op + dt * 32 + q4 * 8 + 4 * hi) = v;
        }
}

// ---------------------------------------------------------------------------
// Kernel C0: one-time Wu fp32 -> bf16 (into dead Q workspace region)
// ---------------------------------------------------------------------------
__global__ __launch_bounds__(256) void wu_conv(const float* __restrict__ Wu, u16* __restrict__ Wub) {
    int i = (blockIdx.x * 256 + threadIdx.x) * 4;
    f32x4 f = *(const f32x4*)(Wu + i);
    u16x4 o = { f2bf(f[0]), f2bf(f[1]), f2bf(f[2]), f2bf(f[3]) };
    *(u16x4*)(Wub + i) = o;
}

// ---------------------------------------------------------------------------
// Kernel C: out = O @ Wub^T + bu.  M=8192, N=768, K=768.  Tile 64x128, BK=32,
// 256 thr.  T14 reg-prefetch of next K-slice.
// ---------------------------------------------------------------------------
__global__ __launch_bounds__(256) void out_gemm(
    const u16* __restrict__ O, const u16* __restrict__ Wub,
    const float* __restrict__ bu, float* __restrict__ out)
{
    __shared__ __align__(16) u16 Al[64][40];
    __shared__ __align__(16) u16 Bl[128][40];
    const int tid = threadIdx.x;
    const int w = tid >> 6, l = tid & 63;
    const int lc = l & 15, lk = l >> 4;
    const int m0 = blockIdx.x * 64, n0 = blockIdx.y * 128;

    const int arow = tid >> 2, acc_ = (tid & 3) * 8;
    const int brow0 = tid >> 2, bcc0 = (tid & 3) * 8;          // chunks 0..255
    const int brow1 = (tid + 256) >> 2, bcc1 = (tid & 3) * 8;  // chunks 256..511

    f32x4 acc[8];
    const f32x4 Z4 = {0.f, 0.f, 0.f, 0.f};
#pragma unroll
    for (int nt = 0; nt < 8; ++nt) acc[nt] = Z4;

    // prologue loads (c0 = 0)
    u16x8 ra = *(const u16x8*)(O + (long)(m0 + arow) * KD + acc_);
    u16x8 rb0 = *(const u16x8*)(Wub + (long)(n0 + brow0) * KD + bcc0);
    u16x8 rb1 = *(const u16x8*)(Wub + (long)(n0 + brow1) * KD + bcc1);

    for (int c0 = 0; c0 < KD; c0 += 32) {
        __syncthreads();
        *(u16x8*)&Al[arow][acc_] = ra;
        *(u16x8*)&Bl[brow0][bcc0] = rb0;
        *(u16x8*)&Bl[brow1][bcc1] = rb1;
        int cn = c0 + 32; if (cn > KD - 32) cn = KD - 32;
        ra = *(const u16x8*)(O + (long)(m0 + arow) * KD + cn + acc_);
        rb0 = *(const u16x8*)(Wub + (long)(n0 + brow0) * KD + cn + bcc0);
        rb1 = *(const u16x8*)(Wub + (long)(n0 + brow1) * KD + cn + bcc1);
        __syncthreads();

        bf16x8 a = cast8(*(const u16x8*)&Al[w * 16 + lc][8 * lk]);
#pragma unroll
        for (int nt = 0; nt < 8; ++nt) {
            u16x8 bb = *(const u16x8*)&Bl[nt * 16 + lc][8 * lk];
            acc[nt] = __builtin_amdgcn_mfma_f32_16x16x32_bf16(a, cast8(bb), acc[nt], 0, 0, 0);
        }
    }

#pragma unroll
    for (int reg = 0; reg < 4; ++reg) {
        int rr = m0 + w * 16 + lk * 4 + reg;
        float* op = out + (long)rr * KD + n0;
#pragma unroll
        for (int nt = 0; nt < 8; ++nt)
            op[nt * 16 + lc] = acc[nt][reg] + bu[n0 + nt * 16 + lc];
    }
}

extern "C" void kernel_launch(void* const* d_in, const int* in_sizes, int n_in,
                              void* d_out, int out_size, void* d_ws, size_t ws_size,
                              hipStream_t stream) {
    const float* x  = (const float*)d_in[0];
    const float* Wq = (const float*)d_in[1];
    const float* Wk = (const float*)d_in[2];
    const float* Wv = (const float*)d_in[3];
    const float* Wu = (const float*)d_in[4];
    const float* bu = (const float*)d_in[5];
    float* out = (float*)d_out;

    u16* ws = (u16*)d_ws;
    const size_t SZ = (size_t)NB * NH * TB * HD;   // per-tensor bf16 elems
    u16* Q   = ws;
    u16* Kq  = ws + SZ;
    u16* VT  = ws + 2 * SZ;   // [bh][96][2048]
    u16* O   = ws + 3 * SZ;
    u16* Wub = ws;            // aliases Q (dead after attn; stream-ordered)

    const float inv4 = 1.0f / powf((float)KD, 0.25f);

    qkv_proj<<<dim3(TB / 64, NB * NH), dim3(256), 0, stream>>>(x, Wq, Wk, Wv, Q, Kq, VT, inv4);
    attn<<<dim3(TB / 256, NB * NH), dim3(512), 0, stream>>>(Q, Kq, VT, O);
    wu_conv<<<dim3((KD * KD) / 1024), dim3(256), 0, stream>>>(Wu, Wub);
    out_gemm<<<dim3((NB * TB) / 64, KD / 128), dim3(256), 0, stream>>>(O, Wub, bu, out);
}